// Round 1
// baseline (375.942 us; speedup 1.0000x reference)
//
#include <hip/hip_runtime.h>

#define N_PTS 32768
#define M_Q   8192
#define C_F   256
#define CH    2048
#define NCH   (N_PTS / CH)   // 16
#define QB    32             // queries per block
#define WQ    8              // queries per wave

__device__ __forceinline__ float rn_mul(float a, float b) { return __fmul_rn(a, b); }
__device__ __forceinline__ float rn_add(float a, float b) { return __fadd_rn(a, b); }

// Pack [x,y,z,b2] per point for both sides into workspace.
__global__ __launch_bounds__(256) void pack_pts(const float* __restrict__ c0,
                                                const float* __restrict__ c1,
                                                float4* __restrict__ pts) {
    int t = blockIdx.x * blockDim.x + threadIdx.x;   // 0 .. 2N-1
    int side = t >> 15;                              // t / N_PTS
    int n = t & (N_PTS - 1);
    const float* c = side ? c1 : c0;
    float x = c[n * 3 + 0], y = c[n * 3 + 1], z = c[n * 3 + 2];
    // numpy: sum(b*b, -1) = (x*x + y*y) + z*z, each op rounded, no fma
    float b2 = rn_add(rn_add(rn_mul(x, x), rn_mul(y, y)), rn_mul(z, z));
    pts[t] = make_float4(x, y, z, b2);
}

__global__ __launch_bounds__(256) void pool_gather(
    const float* __restrict__ src, const float* __restrict__ tgt,
    const float* __restrict__ sc0, const float* __restrict__ sc1,
    const float4* __restrict__ pts, float* __restrict__ out)
{
    __shared__ float4 buf[2][CH];
    __shared__ int sidx[QB];

    int bid  = blockIdx.x;
    int side = bid >> 8;          // 256 blocks per side
    int qblk = bid & 255;
    const float*  feats = side ? tgt : src;
    const float*  sc    = side ? sc1 : sc0;
    const float4* p     = pts + (size_t)side * N_PTS;

    int tid  = threadIdx.x;
    int wave = tid >> 6;
    int lane = tid & 63;
    int q0   = qblk * QB + wave * WQ;

    float ax[WQ], ay[WQ], az[WQ], a2[WQ];
    float d1[WQ], d2[WQ];
    int   i1[WQ], i2[WQ];
#pragma unroll
    for (int qi = 0; qi < WQ; ++qi) {
        int q = q0 + qi;
        float x = sc[q * 3 + 0], y = sc[q * 3 + 1], z = sc[q * 3 + 2];
        ax[qi] = x; ay[qi] = y; az[qi] = z;
        a2[qi] = rn_add(rn_add(rn_mul(x, x), rn_mul(y, y)), rn_mul(z, z));
        d1[qi] = __int_as_float(0x7f800000);  // +inf
        d2[qi] = d1[qi];
        i1[qi] = 0x7fffffff;
        i2[qi] = 0x7fffffff;
    }

    // prologue: stage chunk 0
#pragma unroll
    for (int k = 0; k < CH / 256; ++k)
        buf[0][k * 256 + tid] = p[k * 256 + tid];
    __syncthreads();

    for (int c = 0; c < NCH; ++c) {
        float4 tmp[CH / 256];
        if (c + 1 < NCH) {
#pragma unroll
            for (int k = 0; k < CH / 256; ++k)
                tmp[k] = p[(size_t)(c + 1) * CH + k * 256 + tid];
        }
        const float4* b = buf[c & 1];
        int base = c * CH;
        for (int it = 0; it < CH / 64; ++it) {
            float4 pt = b[it * 64 + lane];
            int pi = base + it * 64 + lane;
#pragma unroll
            for (int qi = 0; qi < WQ; ++qi) {
                // dot: OpenBLAS-style fma chain from 0 -> round(ax*bx) then fmas
                float dot = __builtin_fmaf(az[qi], pt.z,
                             __builtin_fmaf(ay[qi], pt.y, rn_mul(ax[qi], pt.x)));
                float s = rn_add(a2[qi], pt.w);           // a2 + b2 (one rounding)
                float d = __builtin_fmaf(-2.0f, dot, s);  // == round((a2+b2) - 2*dot)
                if (d < d2[qi]) {
                    if (d < d1[qi]) {
                        d2[qi] = d1[qi]; i2[qi] = i1[qi];
                        d1[qi] = d;      i1[qi] = pi;
                    } else {
                        d2[qi] = d;      i2[qi] = pi;
                    }
                }
            }
        }
        if (c + 1 < NCH) {
#pragma unroll
            for (int k = 0; k < CH / 256; ++k)
                buf[(c + 1) & 1][k * 256 + tid] = tmp[k];
        }
        __syncthreads();
    }

    // cross-lane lexicographic two-smallest merge (butterfly over 64 lanes)
#pragma unroll
    for (int off = 1; off < 64; off <<= 1) {
#pragma unroll
        for (int qi = 0; qi < WQ; ++qi) {
            float od1 = __shfl_xor(d1[qi], off);
            int   oi1 = __shfl_xor(i1[qi], off);
            float od2 = __shfl_xor(d2[qi], off);
            int   oi2 = __shfl_xor(i2[qi], off);
            bool oless = (od1 < d1[qi]) || (od1 == d1[qi] && oi1 < i1[qi]);
            float n1d, n2d; int n1i, n2i;
            if (oless) {
                n1d = od1; n1i = oi1;
                bool t = (d1[qi] < od2) || (d1[qi] == od2 && i1[qi] < oi2);
                n2d = t ? d1[qi] : od2;
                n2i = t ? i1[qi] : oi2;
            } else {
                n1d = d1[qi]; n1i = i1[qi];
                bool t = (od1 < d2[qi]) || (od1 == d2[qi] && oi1 < i2[qi]);
                n2d = t ? od1 : d2[qi];
                n2i = t ? oi1 : i2[qi];
            }
            d1[qi] = n1d; i1[qi] = n1i;
            d2[qi] = n2d; i2[qi] = n2i;
        }
    }

    if (lane == 0) {
#pragma unroll
        for (int qi = 0; qi < WQ; ++qi) sidx[wave * WQ + qi] = i2[qi];
    }
    __syncthreads();

    // fused gather: 32 rows of 256 floats; one float4 per lane per row
#pragma unroll
    for (int j = 0; j < WQ; ++j) {
        int r = wave * WQ + j;
        int row = sidx[r];
        const float4* sp = (const float4*)(feats + (size_t)row * C_F);
        float4* dp = (float4*)(out + ((size_t)side * M_Q + qblk * QB + r) * (size_t)C_F);
        dp[lane] = sp[lane];
    }
}

extern "C" void kernel_launch(void* const* d_in, const int* in_sizes, int n_in,
                              void* d_out, int out_size, void* d_ws, size_t ws_size,
                              hipStream_t stream) {
    const float* src  = (const float*)d_in[0];
    const float* tgt  = (const float*)d_in[1];
    const float* c0   = (const float*)d_in[2];  // src_coords   (N,3)
    const float* c1   = (const float*)d_in[3];  // tgt_coords   (N,3)
    const float* sh0  = (const float*)d_in[4];  // src_shortcut (M,3)
    const float* sh1  = (const float*)d_in[5];  // tgt_shortcut (M,3)
    float4* pts = (float4*)d_ws;                // 2*N*16B = 1 MB
    float*  out = (float*)d_out;

    hipLaunchKernelGGL(pack_pts, dim3(2 * N_PTS / 256), dim3(256), 0, stream,
                       c0, c1, pts);
    hipLaunchKernelGGL(pool_gather, dim3(2 * (M_Q / QB)), dim3(256), 0, stream,
                       src, tgt, sh0, sh1, pts, out);
}

// Round 2
// 206.692 us; speedup vs baseline: 1.8188x; 1.8188x over previous
//
#include <hip/hip_runtime.h>

#define N_PTS 32768
#define M_Q   8192
#define C_F   256
#define QB    8              // queries per block (all 4 waves share them)
#define NW    4              // waves per block
#define WPTS  (N_PTS / NW)   // 8192 points scanned per wave
#define NIT   (WPTS / 64)    // 128 iterations per wave

__device__ __forceinline__ float rn_mul(float a, float b) { return __fmul_rn(a, b); }
__device__ __forceinline__ float rn_add(float a, float b) { return __fadd_rn(a, b); }

// Pack [x,y,z,b2] per point for both sides into workspace.
__global__ __launch_bounds__(256) void pack_pts(const float* __restrict__ c0,
                                                const float* __restrict__ c1,
                                                float4* __restrict__ pts) {
    int t = blockIdx.x * blockDim.x + threadIdx.x;   // 0 .. 2N-1
    int side = t >> 15;
    int n = t & (N_PTS - 1);
    const float* c = side ? c1 : c0;
    float x = c[n * 3 + 0], y = c[n * 3 + 1], z = c[n * 3 + 2];
    // numpy: sum(b*b, -1) = (x*x + y*y) + z*z, each op rounded, no fma
    float b2 = rn_add(rn_add(rn_mul(x, x), rn_mul(y, y)), rn_mul(z, z));
    pts[t] = make_float4(x, y, z, b2);
}

__global__ __launch_bounds__(256, 4) void pool_gather(
    const float* __restrict__ src, const float* __restrict__ tgt,
    const float* __restrict__ sc0, const float* __restrict__ sc1,
    const float4* __restrict__ pts, float* __restrict__ out)
{
    __shared__ float md1[NW][QB], md2[NW][QB];
    __shared__ int   mi1[NW][QB], mi2[NW][QB];
    __shared__ int   sidx[QB];

    int bid  = blockIdx.x;
    int side = bid >> 10;          // 1024 blocks per side
    int qb   = bid & 1023;
    const float*  feats = side ? tgt : src;
    const float*  sc    = side ? sc1 : sc0;

    int tid  = threadIdx.x;
    int wave = tid >> 6;
    int lane = tid & 63;
    int q0   = qb * QB;
    int wbase = wave * WPTS;
    const float4* P = pts + (size_t)side * N_PTS + wbase;

    float ax[QB], ay[QB], az[QB], a2[QB];
    float d1[QB], d2[QB];
    int   i1[QB], i2[QB];
#pragma unroll
    for (int qi = 0; qi < QB; ++qi) {
        int q = q0 + qi;
        float x = sc[q * 3 + 0], y = sc[q * 3 + 1], z = sc[q * 3 + 2];
        ax[qi] = x; ay[qi] = y; az[qi] = z;
        a2[qi] = rn_add(rn_add(rn_mul(x, x), rn_mul(y, y)), rn_mul(z, z));
        d1[qi] = __int_as_float(0x7f800000);  // +inf
        d2[qi] = d1[qi];
        i1[qi] = 0x7fffffff;
        i2[qi] = 0x7fffffff;
    }

    // streaming scan with 2-deep prefetch; pts slice is L2-resident (1 MB total)
    float4 cur = P[lane];
    float4 nx  = P[64 + lane];
    for (int it = 0; it < NIT; ++it) {
        int pf = it + 2 < NIT ? it + 2 : NIT - 1;
        float4 nn = P[pf * 64 + lane];
        int pi = wbase + it * 64 + lane;
#pragma unroll
        for (int qi = 0; qi < QB; ++qi) {
            float dot = __builtin_fmaf(az[qi], cur.z,
                         __builtin_fmaf(ay[qi], cur.y, rn_mul(ax[qi], cur.x)));
            float d = __builtin_fmaf(-2.0f, dot, rn_add(a2[qi], cur.w));
            bool lt1 = d < d1[qi];
            bool lt2 = d < d2[qi];
            d2[qi] = lt1 ? d1[qi] : (lt2 ? d : d2[qi]);
            i2[qi] = lt1 ? i1[qi] : (lt2 ? pi : i2[qi]);
            d1[qi] = lt1 ? d : d1[qi];
            i1[qi] = lt1 ? pi : i1[qi];
        }
        cur = nx; nx = nn;
    }

    // cross-lane lexicographic two-smallest merge (butterfly over 64 lanes)
#pragma unroll
    for (int off = 1; off < 64; off <<= 1) {
#pragma unroll
        for (int qi = 0; qi < QB; ++qi) {
            float od1 = __shfl_xor(d1[qi], off);
            int   oi1 = __shfl_xor(i1[qi], off);
            float od2 = __shfl_xor(d2[qi], off);
            int   oi2 = __shfl_xor(i2[qi], off);
            bool oless = (od1 < d1[qi]) || (od1 == d1[qi] && oi1 < i1[qi]);
            float n1d, n2d; int n1i, n2i;
            if (oless) {
                n1d = od1; n1i = oi1;
                bool t = (d1[qi] < od2) || (d1[qi] == od2 && i1[qi] < oi2);
                n2d = t ? d1[qi] : od2;
                n2i = t ? i1[qi] : oi2;
            } else {
                n1d = d1[qi]; n1i = i1[qi];
                bool t = (od1 < d2[qi]) || (od1 == d2[qi] && oi1 < i2[qi]);
                n2d = t ? od1 : d2[qi];
                n2i = t ? oi1 : i2[qi];
            }
            d1[qi] = n1d; i1[qi] = n1i;
            d2[qi] = n2d; i2[qi] = n2i;
        }
    }

    if (lane == 0) {
#pragma unroll
        for (int qi = 0; qi < QB; ++qi) {
            md1[wave][qi] = d1[qi]; mi1[wave][qi] = i1[qi];
            md2[wave][qi] = d2[qi]; mi2[wave][qi] = i2[qi];
        }
    }
    __syncthreads();

    // merge the 4 waves' candidate pairs (disjoint ascending index ranges)
    if (tid < QB) {
        float b1 = md1[0][tid], b2 = md2[0][tid];
        int   j1 = mi1[0][tid], j2 = mi2[0][tid];
#pragma unroll
        for (int w = 1; w < NW; ++w) {
#pragma unroll
            for (int s = 0; s < 2; ++s) {
                float d = s ? md2[w][tid] : md1[w][tid];
                int   i = s ? mi2[w][tid] : mi1[w][tid];
                bool lt1 = (d < b1) || (d == b1 && i < j1);
                bool lt2 = (d < b2) || (d == b2 && i < j2);
                b2 = lt1 ? b1 : (lt2 ? d : b2);
                j2 = lt1 ? j1 : (lt2 ? i : j2);
                b1 = lt1 ? d : b1;
                j1 = lt1 ? i : j1;
            }
        }
        sidx[tid] = j2;
    }
    __syncthreads();

    // fused gather: QB rows of 256 floats; 32 threads per row, 2 float4 each
    int qi = tid >> 5;
    int cj = tid & 31;
    int row = sidx[qi];
    const float4* sp = (const float4*)(feats + (size_t)row * C_F);
    float4* dp = (float4*)(out + ((size_t)side * M_Q + q0 + qi) * (size_t)C_F);
    dp[cj]      = sp[cj];
    dp[cj + 32] = sp[cj + 32];
}

extern "C" void kernel_launch(void* const* d_in, const int* in_sizes, int n_in,
                              void* d_out, int out_size, void* d_ws, size_t ws_size,
                              hipStream_t stream) {
    const float* src  = (const float*)d_in[0];
    const float* tgt  = (const float*)d_in[1];
    const float* c0   = (const float*)d_in[2];  // src_coords   (N,3)
    const float* c1   = (const float*)d_in[3];  // tgt_coords   (N,3)
    const float* sh0  = (const float*)d_in[4];  // src_shortcut (M,3)
    const float* sh1  = (const float*)d_in[5];  // tgt_shortcut (M,3)
    float4* pts = (float4*)d_ws;                // 2*N*16B = 1 MB
    float*  out = (float*)d_out;

    hipLaunchKernelGGL(pack_pts, dim3(2 * N_PTS / 256), dim3(256), 0, stream,
                       c0, c1, pts);
    hipLaunchKernelGGL(pool_gather, dim3(2 * (M_Q / QB)), dim3(256), 0, stream,
                       src, tgt, sh0, sh1, pts, out);
}

// Round 3
// 178.871 us; speedup vs baseline: 2.1018x; 1.1555x over previous
//
#include <hip/hip_runtime.h>

#define N_PTS 32768
#define M_Q   8192
#define C_F   256
#define QB    8              // queries per block
#define NW    4              // waves per block
#define NS    2              // point-range splits per query block
#define SPTS  (N_PTS / NS)   // 16384 points per split
#define WPTS  (SPTS / NW)    // 4096 points per wave
#define NIT   (WPTS / 64)    // 64 iterations per wave
#define NQB   (M_Q / QB)     // 1024 query blocks per side

__device__ __forceinline__ float rn_mul(float a, float b) { return __fmul_rn(a, b); }
__device__ __forceinline__ float rn_add(float a, float b) { return __fadd_rn(a, b); }

// Pack [x,y,z,b2] per point for both sides into workspace.
__global__ __launch_bounds__(256) void pack_pts(const float* __restrict__ c0,
                                                const float* __restrict__ c1,
                                                float4* __restrict__ pts) {
    int t = blockIdx.x * blockDim.x + threadIdx.x;   // 0 .. 2N-1
    int side = t >> 15;
    int n = t & (N_PTS - 1);
    const float* c = side ? c1 : c0;
    float x = c[n * 3 + 0], y = c[n * 3 + 1], z = c[n * 3 + 2];
    // numpy: sum(b*b, -1) = (x*x + y*y) + z*z, each op rounded, no fma
    float b2 = rn_add(rn_add(rn_mul(x, x), rn_mul(y, y)), rn_mul(z, z));
    pts[t] = make_float4(x, y, z, b2);
}

// Phase 1: per (side, query-block, split) compute top-2 (d,i) for 8 queries
// over 16384 points; write partials to ws.
__global__ __launch_bounds__(256) void pool_phase1(
    const float* __restrict__ sc0, const float* __restrict__ sc1,
    const float4* __restrict__ pts, int4* __restrict__ part)
{
    __shared__ float md1[NW][QB], md2[NW][QB];
    __shared__ int   mi1[NW][QB], mi2[NW][QB];

    int bid  = blockIdx.x;                 // 2 * NQB * NS
    int side = bid >> 11;
    int r    = bid & 2047;
    int qb   = r >> 1;
    int sp   = r & 1;
    const float* sc = side ? sc1 : sc0;

    int tid  = threadIdx.x;
    int wave = tid >> 6;
    int lane = tid & 63;
    int q0   = qb * QB;
    int wbase = sp * SPTS + wave * WPTS;
    const float4* P = pts + (size_t)side * N_PTS + wbase;

    float ax[QB], ay[QB], az[QB], a2[QB];
    float d1[QB], d2[QB];
    int   i1[QB], i2[QB];
#pragma unroll
    for (int qi = 0; qi < QB; ++qi) {
        int q = q0 + qi;
        float x = sc[q * 3 + 0], y = sc[q * 3 + 1], z = sc[q * 3 + 2];
        ax[qi] = x; ay[qi] = y; az[qi] = z;
        a2[qi] = rn_add(rn_add(rn_mul(x, x), rn_mul(y, y)), rn_mul(z, z));
        d1[qi] = __int_as_float(0x7f800000);  // +inf
        d2[qi] = d1[qi];
        i1[qi] = 0x7fffffff;
        i2[qi] = 0x7fffffff;
    }

#pragma unroll 4
    for (int it = 0; it < NIT; ++it) {
        float4 pt = P[it * 64 + lane];
        int pi = wbase + it * 64 + lane;
#pragma unroll
        for (int qi = 0; qi < QB; ++qi) {
            float dot = __builtin_fmaf(az[qi], pt.z,
                         __builtin_fmaf(ay[qi], pt.y, rn_mul(ax[qi], pt.x)));
            float d = __builtin_fmaf(-2.0f, dot, rn_add(a2[qi], pt.w));
            bool lt1 = d < d1[qi];
            bool lt2 = d < d2[qi];
            d2[qi] = lt1 ? d1[qi] : (lt2 ? d : d2[qi]);
            i2[qi] = lt1 ? i1[qi] : (lt2 ? pi : i2[qi]);
            d1[qi] = lt1 ? d : d1[qi];
            i1[qi] = lt1 ? pi : i1[qi];
        }
    }

    // cross-lane lexicographic two-smallest merge (butterfly over 64 lanes)
#pragma unroll
    for (int off = 1; off < 64; off <<= 1) {
#pragma unroll
        for (int qi = 0; qi < QB; ++qi) {
            float od1 = __shfl_xor(d1[qi], off);
            int   oi1 = __shfl_xor(i1[qi], off);
            float od2 = __shfl_xor(d2[qi], off);
            int   oi2 = __shfl_xor(i2[qi], off);
            bool oless = (od1 < d1[qi]) || (od1 == d1[qi] && oi1 < i1[qi]);
            float n1d, n2d; int n1i, n2i;
            if (oless) {
                n1d = od1; n1i = oi1;
                bool t = (d1[qi] < od2) || (d1[qi] == od2 && i1[qi] < oi2);
                n2d = t ? d1[qi] : od2;
                n2i = t ? i1[qi] : oi2;
            } else {
                n1d = d1[qi]; n1i = i1[qi];
                bool t = (od1 < d2[qi]) || (od1 == d2[qi] && oi1 < i2[qi]);
                n2d = t ? od1 : d2[qi];
                n2i = t ? oi1 : i2[qi];
            }
            d1[qi] = n1d; i1[qi] = n1i;
            d2[qi] = n2d; i2[qi] = n2i;
        }
    }

    if (lane == 0) {
#pragma unroll
        for (int qi = 0; qi < QB; ++qi) {
            md1[wave][qi] = d1[qi]; mi1[wave][qi] = i1[qi];
            md2[wave][qi] = d2[qi]; mi2[wave][qi] = i2[qi];
        }
    }
    __syncthreads();

    // merge the 4 waves' candidate pairs; write partial top-2 for this split
    if (tid < QB) {
        float b1 = md1[0][tid], b2 = md2[0][tid];
        int   j1 = mi1[0][tid], j2 = mi2[0][tid];
#pragma unroll
        for (int w = 1; w < NW; ++w) {
#pragma unroll
            for (int s = 0; s < 2; ++s) {
                float d = s ? md2[w][tid] : md1[w][tid];
                int   i = s ? mi2[w][tid] : mi1[w][tid];
                bool lt1 = (d < b1) || (d == b1 && i < j1);
                bool lt2 = (d < b2) || (d == b2 && i < j2);
                b2 = lt1 ? b1 : (lt2 ? d : b2);
                j2 = lt1 ? j1 : (lt2 ? i : j2);
                b1 = lt1 ? d : b1;
                j1 = lt1 ? i : j1;
            }
        }
        int qg = side * M_Q + q0 + tid;   // global query id
        part[qg * NS + sp] = make_int4(__float_as_int(b1), j1,
                                       __float_as_int(b2), j2);
    }
}

// Phase 2: merge the NS partials per query, gather feature rows.
__global__ __launch_bounds__(256) void merge_gather(
    const float* __restrict__ src, const float* __restrict__ tgt,
    const int4* __restrict__ part, float* __restrict__ out)
{
    __shared__ int sidx[QB];

    int bid  = blockIdx.x;          // 2 * NQB
    int side = bid >> 10;
    int qb   = bid & 1023;
    const float* feats = side ? tgt : src;
    int tid = threadIdx.x;
    int q0  = qb * QB;

    if (tid < QB) {
        int qg = side * M_Q + q0 + tid;
        int4 p0 = part[qg * NS + 0];
        float b1 = __int_as_float(p0.x), b2 = __int_as_float(p0.z);
        int   j1 = p0.y,                 j2 = p0.w;
#pragma unroll
        for (int sp = 1; sp < NS; ++sp) {
            int4 p = part[qg * NS + sp];
#pragma unroll
            for (int s = 0; s < 2; ++s) {
                float d = __int_as_float(s ? p.z : p.x);
                int   i = s ? p.w : p.y;
                bool lt1 = (d < b1) || (d == b1 && i < j1);
                bool lt2 = (d < b2) || (d == b2 && i < j2);
                b2 = lt1 ? b1 : (lt2 ? d : b2);
                j2 = lt1 ? j1 : (lt2 ? i : j2);
                b1 = lt1 ? d : b1;
                j1 = lt1 ? i : j1;
            }
        }
        sidx[tid] = j2;
    }
    __syncthreads();

    // gather: QB rows of 256 floats; 32 threads per row, 2 float4 each
    int qi = tid >> 5;
    int cj = tid & 31;
    int row = sidx[qi];
    const float4* sp = (const float4*)(feats + (size_t)row * C_F);
    float4* dp = (float4*)(out + ((size_t)side * M_Q + q0 + qi) * (size_t)C_F);
    dp[cj]      = sp[cj];
    dp[cj + 32] = sp[cj + 32];
}

extern "C" void kernel_launch(void* const* d_in, const int* in_sizes, int n_in,
                              void* d_out, int out_size, void* d_ws, size_t ws_size,
                              hipStream_t stream) {
    const float* src  = (const float*)d_in[0];
    const float* tgt  = (const float*)d_in[1];
    const float* c0   = (const float*)d_in[2];  // src_coords   (N,3)
    const float* c1   = (const float*)d_in[3];  // tgt_coords   (N,3)
    const float* sh0  = (const float*)d_in[4];  // src_shortcut (M,3)
    const float* sh1  = (const float*)d_in[5];  // tgt_shortcut (M,3)
    float* out = (float*)d_out;

    float4* pts  = (float4*)d_ws;                         // 2*N*16B = 1 MB
    int4*   part = (int4*)((char*)d_ws + (size_t)2 * N_PTS * sizeof(float4));
    // partials: 2*M_Q*NS*16B = 512 KB

    hipLaunchKernelGGL(pack_pts, dim3(2 * N_PTS / 256), dim3(256), 0, stream,
                       c0, c1, pts);
    hipLaunchKernelGGL(pool_phase1, dim3(2 * NQB * NS), dim3(256), 0, stream,
                       sh0, sh1, pts, part);
    hipLaunchKernelGGL(merge_gather, dim3(2 * NQB), dim3(256), 0, stream,
                       src, tgt, part, out);
}